// Round 9
// baseline (913.318 us; speedup 1.0000x reference)
//
#include <hip/hip_runtime.h>

#define DIMS 1024
#define NB 1024         // pass blocks
#define TPB 256
#define NWAVE 4
#define CB 64           // fallback combine blocks
#define ACC_STRIDE 1088 // per-step accumulator stride (1024 dims + l + pad)

#if defined(__has_builtin)
#if __has_builtin(__builtin_amdgcn_sdot8)
#define HAVE_SDOT8 1
#endif
#endif
#ifndef HAVE_SDOT8
#define HAVE_SDOT8 0
#endif

__device__ __forceinline__ float wave_sum(float v) {
#pragma unroll
  for (int s = 32; s; s >>= 1) v += __shfl_xor(v, s, 64);
  return v;
}

__device__ __forceinline__ float wave_max(float v) {
#pragma unroll
  for (int s = 32; s; s >>= 1) v = fmaxf(v, __shfl_xor(v, s, 64));
  return v;
}

__device__ __forceinline__ int nib(unsigned int w, int i) {
  return (int)(w << (28 - 4 * i)) >> 28;
}

// dot of 32 int4 nibbles (uint4) against q nibbles (uint4)
__device__ __forceinline__ int dot32(uint4 x, uint4 qc) {
#if HAVE_SDOT8
  int t = __builtin_amdgcn_sdot8((int)x.x, (int)qc.x, 0, false);
  t = __builtin_amdgcn_sdot8((int)x.y, (int)qc.y, t, false);
  t = __builtin_amdgcn_sdot8((int)x.z, (int)qc.z, t, false);
  return __builtin_amdgcn_sdot8((int)x.w, (int)qc.w, t, false);
#else
  int t = 0;
#pragma unroll
  for (int i = 0; i < 8; ++i) t += __mul24(nib(x.x, i), nib(qc.x, i));
#pragma unroll
  for (int i = 0; i < 8; ++i) t += __mul24(nib(x.y, i), nib(qc.y, i));
#pragma unroll
  for (int i = 0; i < 8; ++i) t += __mul24(nib(x.z, i), nib(qc.z, i));
#pragma unroll
  for (int i = 0; i < 8; ++i) t += __mul24(nib(x.w, i), nib(qc.w, i));
  return t;
#endif
}

// encode 16 f32 (4x float4) -> 16 signed int4 nibbles (uint2); nibble order = c[0..15]
__device__ __forceinline__ uint2 enc_i4(const float4* xv, float scale) {
  unsigned int w[2];
#pragma unroll
  for (int h = 0; h < 2; ++h) {
    unsigned int a = 0;
#pragma unroll
    for (int jj = 0; jj < 2; ++jj) {
      float4 t = xv[h * 2 + jj];
      a |= ((unsigned int)((int)rintf(t.x * scale) & 0xF)) << (jj * 16 + 0);
      a |= ((unsigned int)((int)rintf(t.y * scale) & 0xF)) << (jj * 16 + 4);
      a |= ((unsigned int)((int)rintf(t.z * scale) & 0xF)) << (jj * 16 + 8);
      a |= ((unsigned int)((int)rintf(t.w * scale) & 0xF)) << (jj * 16 + 12);
    }
    w[h] = a;
  }
  return make_uint2(w[0], w[1]);
}

// ---------------- f32 pass (step 0): fixed-offset softmax, quant-write, atomic acc0 ----
template <int STEP0, int MODE>
__global__ __launch_bounds__(TPB) void pass_f32(
    const float* __restrict__ ca3,
    const float* __restrict__ q,
    float* __restrict__ invnorm,
    uint2* __restrict__ qmat,
    float2* __restrict__ rowmeta,
    float* __restrict__ accbuf,
    float* __restrict__ part_acc,
    float* __restrict__ part_l,
    int rows_per_block) {
  const int tid  = threadIdx.x;
  const int lane = tid & 63;
  const int wv   = tid >> 6;
  const int bid  = blockIdx.x;

  const float4* q4 = (const float4*)q;
  float4 qv[4];
  float qss = 0.f;
#pragma unroll
  for (int j = 0; j < 4; ++j) {
    float4 t = q4[j * 64 + lane];
    qv[j] = t;
    qss += t.x * t.x + t.y * t.y + t.z * t.z + t.w * t.w;
  }
  qss = wave_sum(qss);
  const float inv_qn = 1.0f / fmaxf(sqrtf(qss), 1e-8f);

  const int rpw = rows_per_block >> 2;
  const long long row0 = (long long)bid * rows_per_block + (long long)wv * rpw;

  float l = 0.f;
  float4 acc[4];
#pragma unroll
  for (int j = 0; j < 4; ++j) acc[j] = make_float4(0.f, 0.f, 0.f, 0.f);

  for (int r = 0; r < rpw; r += 2) {
    const long long rowA = row0 + r;
    const long long rowB = rowA + 1;
    const float4* xA4 = (const float4*)(ca3 + rowA * (long long)DIMS);
    const float4* xB4 = (const float4*)(ca3 + rowB * (long long)DIMS);
    float innA = 0.f, innB = 0.f;
    if (!STEP0) { innA = invnorm[rowA]; innB = invnorm[rowB]; }
    float4 xa[4], xb[4];
#pragma unroll
    for (int j = 0; j < 4; ++j) xa[j] = xA4[j * 64 + lane];
#pragma unroll
    for (int j = 0; j < 4; ++j) xb[j] = xB4[j * 64 + lane];

    float dA = 0.f, dB = 0.f, rnA = 0.f, rnB = 0.f, mxA = 0.f, mxB = 0.f;
#pragma unroll
    for (int j = 0; j < 4; ++j) {
      dA += xa[j].x * qv[j].x + xa[j].y * qv[j].y + xa[j].z * qv[j].z + xa[j].w * qv[j].w;
      dB += xb[j].x * qv[j].x + xb[j].y * qv[j].y + xb[j].z * qv[j].z + xb[j].w * qv[j].w;
      if (STEP0) {
        rnA += xa[j].x * xa[j].x + xa[j].y * xa[j].y + xa[j].z * xa[j].z + xa[j].w * xa[j].w;
        rnB += xb[j].x * xb[j].x + xb[j].y * xb[j].y + xb[j].z * xb[j].z + xb[j].w * xb[j].w;
      }
      if (MODE) {
        mxA = fmaxf(mxA, fmaxf(fmaxf(fabsf(xa[j].x), fabsf(xa[j].y)),
                               fmaxf(fabsf(xa[j].z), fabsf(xa[j].w))));
        mxB = fmaxf(mxB, fmaxf(fmaxf(fabsf(xb[j].x), fabsf(xb[j].y)),
                               fmaxf(fabsf(xb[j].z), fabsf(xb[j].w))));
      }
    }
    dA = wave_sum(dA);
    dB = wave_sum(dB);
    if (STEP0) {
      rnA = wave_sum(rnA);
      rnB = wave_sum(rnB);
      innA = 1.0f / fmaxf(sqrtf(rnA), 1e-8f);
      innB = 1.0f / fmaxf(sqrtf(rnB), 1e-8f);
      if (lane == 0) { invnorm[rowA] = innA; invnorm[rowB] = innB; }
    }
    if (MODE) {
      mxA = wave_max(mxA);
      mxB = wave_max(mxB);
      const float scA = 7.0f / fmaxf(mxA, 1e-20f);
      const float scB = 7.0f / fmaxf(mxB, 1e-20f);
      qmat[rowA * 64 + lane] = enc_i4(xa, scA);
      qmat[rowB * 64 + lane] = enc_i4(xb, scB);
      if (lane == 0) {
        const float isA = mxA * (1.0f / 7.0f);
        const float isB = mxB * (1.0f / 7.0f);
        rowmeta[rowA] = make_float2(isA * innA, isA);
        rowmeta[rowB] = make_float2(isB * innB, isB);
      }
    }
    const float pA = __expf(dA * innA * inv_qn - 1.0f);
    const float pB = __expf(dB * innB * inv_qn - 1.0f);
    l += pA + pB;
#pragma unroll
    for (int j = 0; j < 4; ++j) {
      acc[j].x += pA * xa[j].x + pB * xb[j].x;
      acc[j].y += pA * xa[j].y + pB * xb[j].y;
      acc[j].z += pA * xa[j].z + pB * xb[j].z;
      acc[j].w += pA * xa[j].w + pB * xb[j].w;
    }
  }

  // ---- block combine ----
  __shared__ float s_l[NWAVE];
  __shared__ float s_lin[NWAVE * DIMS];  // 16 KB
  if (lane == 0) s_l[wv] = l;
#pragma unroll
  for (int j = 0; j < 4; ++j)
    ((float4*)s_lin)[wv * (DIMS / 4) + j * 64 + lane] = acc[j];
  __syncthreads();
  float4 sum = ((float4*)s_lin)[tid];
#pragma unroll
  for (int w = 1; w < NWAVE; ++w) {
    float4 b = ((float4*)s_lin)[w * (DIMS / 4) + tid];
    sum.x += b.x; sum.y += b.y; sum.z += b.z; sum.w += b.w;
  }
  if (MODE) {
    atomicAdd(&accbuf[4 * tid + 0], sum.x);
    atomicAdd(&accbuf[4 * tid + 1], sum.y);
    atomicAdd(&accbuf[4 * tid + 2], sum.z);
    atomicAdd(&accbuf[4 * tid + 3], sum.w);
    if (tid == 0) atomicAdd(&accbuf[1024], s_l[0] + s_l[1] + s_l[2] + s_l[3]);
  } else {
    ((float4*)part_acc)[bid * (DIMS / 4) + tid] = sum;
    if (tid == 0) part_l[bid] = s_l[0] + s_l[1] + s_l[2] + s_l[3];
  }
}

// ---------------- Kernel A: dots -> pai[N] (pair-packed uint4, half-wave reduce) ------
__global__ __launch_bounds__(TPB, 4) void pass_dot(
    const uint4* __restrict__ qmat4,    // pair = 64 uint4 (lane<32 rowA, lane>=32 rowB)
    const float* __restrict__ cur0,
    const float2* __restrict__ rowmeta,
    float* __restrict__ accbuf,
    int* __restrict__ pai,
    int step,
    int rows_per_block) {
  const int tid  = threadIdx.x;
  const int lane = tid & 63;
  const int wv   = tid >> 6;
  const int bid  = blockIdx.x;
  const int h    = lane >> 5;  // 0: row 2p, 1: row 2p+1

  __shared__ uint2 s_q[64];
  __shared__ float s_qscale;
  __shared__ float s_l[NWAVE];

  // ---- prologue (wave 0): reconstruct cur_step, quantize q ----
  if (wv == 0) {
    float c[16];
    float w0 = 1.0f;
    for (int t = 0; t < step; ++t) w0 *= 0.2f;
    const float4* c04 = (const float4*)cur0;
#pragma unroll
    for (int jj = 0; jj < 4; ++jj) {
      float4 t = c04[jj * 64 + lane];
      c[4 * jj + 0] = w0 * t.x; c[4 * jj + 1] = w0 * t.y;
      c[4 * jj + 2] = w0 * t.z; c[4 * jj + 3] = w0 * t.w;
    }
    for (int j = 0; j < step; ++j) {
      const float lj = accbuf[j * ACC_STRIDE + 1024];
      float coef = 0.8f / lj;
      for (int t = j; t < step - 1; ++t) coef *= 0.2f;
      const float4* aj = (const float4*)(accbuf + j * ACC_STRIDE);
#pragma unroll
      for (int jj = 0; jj < 4; ++jj) {
        float4 t = aj[jj * 64 + lane];
        c[4 * jj + 0] += coef * t.x; c[4 * jj + 1] += coef * t.y;
        c[4 * jj + 2] += coef * t.z; c[4 * jj + 3] += coef * t.w;
      }
    }
    float qss = 0.f, qmx = 0.f;
#pragma unroll
    for (int i = 0; i < 16; ++i) { qss += c[i] * c[i]; qmx = fmaxf(qmx, fabsf(c[i])); }
    qss = wave_sum(qss);
    qmx = wave_max(qmx);
    const float inv_qn = 1.0f / fmaxf(sqrtf(qss), 1e-8f);
    const float sq = 7.0f / fmaxf(qmx, 1e-20f);
    unsigned int qq0 = 0, qq1 = 0;
#pragma unroll
    for (int i = 0; i < 8; ++i)
      qq0 |= ((unsigned int)((int)rintf(c[i] * sq) & 0xF)) << (4 * i);
#pragma unroll
    for (int i = 0; i < 8; ++i)
      qq1 |= ((unsigned int)((int)rintf(c[8 + i] * sq) & 0xF)) << (4 * i);
    s_q[lane] = make_uint2(qq0, qq1);
    if (lane == 0) s_qscale = (qmx * (1.0f / 7.0f)) * inv_qn;
  }
  __syncthreads();
  const uint4 qv = ((const uint4*)s_q)[lane & 31];
  const float qscale = s_qscale;

  const long long wrow0 = (long long)bid * rows_per_block + (long long)wv * (rows_per_block >> 2);
  const uint4* base = qmat4 + (wrow0 >> 1) * 64;  // pair base
  const int npairs = rows_per_block >> 3;         // pairs per wave (32)

  float l_acc = 0.f;
  uint4 cu[8], nx[8];
#pragma unroll
  for (int k = 0; k < 8; ++k) cu[k] = base[k * 64 + lane];

  const int ngrp = npairs >> 3;  // 4 groups of 8 pairs
  for (int g = 0; g < ngrp; ++g) {
    const int gn = (g + 1 < ngrp) ? (g + 1) : 0;
#pragma unroll
    for (int k = 0; k < 8; ++k) nx[k] = base[(gn * 8 + k) * 64 + lane];

    int d[8];
#pragma unroll
    for (int k = 0; k < 8; ++k) d[k] = dot32(cu[k], qv);
    // 5-step half-wave butterfly, 8 chains interleaved
#pragma unroll
    for (int s = 16; s; s >>= 1)
#pragma unroll
      for (int k = 0; k < 8; ++k) d[k] += __shfl_xor(d[k], s, 64);
#pragma unroll
    for (int k = 0; k < 8; ++k) {
      const long long rowidx = wrow0 + (long long)(g * 8 + k) * 2 + h;
      const float2 mt = rowmeta[rowidx];
      const float pw = __expf((float)d[k] * mt.x * qscale - 1.0f);
      l_acc += pw;
      if ((lane & 31) == 0) pai[rowidx] = (int)(pw * mt.y * 1048576.0f + 0.5f);
    }
#pragma unroll
    for (int k = 0; k < 8; ++k) cu[k] = nx[k];
  }

  const float lt = wave_sum(l_acc) * 0.03125f;  // 32 lanes per half held same pw
  if (lane == 0) s_l[wv] = lt;
  __syncthreads();
  if (tid == 0)
    atomicAdd(&accbuf[step * ACC_STRIDE + 1024], s_l[0] + s_l[1] + s_l[2] + s_l[3]);
}

// ---------------- Kernel B: weighted accumulate (no reductions, no exp) --------------
__global__ __launch_bounds__(TPB, 4) void pass_acc(
    const uint2* __restrict__ qmat,     // row = 64 uint2
    const int* __restrict__ pai,
    float* __restrict__ accbuf,
    int step,
    int rows_per_block) {
  const int tid  = threadIdx.x;
  const int lane = tid & 63;
  const int wv   = tid >> 6;
  const int bid  = blockIdx.x;

  __shared__ int s_pai[TPB];             // rows_per_block = 256
  __shared__ float s_lin[NWAVE * DIMS];  // 16 KB

  const long long rowbase = (long long)bid * rows_per_block;
  s_pai[tid] = pai[rowbase + tid];
  __syncthreads();

  const int w0 = wv * (rows_per_block >> 2);  // local row base (64 rows/wave)
  const uint2* base = qmat + (rowbase + w0) * 64 + lane;

  int acc_i[16];
#pragma unroll
  for (int i = 0; i < 16; ++i) acc_i[i] = 0;

  uint2 cu[16], nx[16];
#pragma unroll
  for (int k = 0; k < 16; ++k) cu[k] = base[k * 64];

  const int ngrp = rows_per_block >> 6;  // 4 groups of 16 rows
  for (int g = 0; g < ngrp; ++g) {
    const int gn = (g + 1 < ngrp) ? (g + 1) : 0;
#pragma unroll
    for (int k = 0; k < 16; ++k) nx[k] = base[(gn * 16 + k) * 64];
#pragma unroll
    for (int k = 0; k < 16; ++k) {
      const int pk = s_pai[w0 + g * 16 + k];  // LDS broadcast
#pragma unroll
      for (int i = 0; i < 8; ++i) acc_i[i]     += __mul24(pk, nib(cu[k].x, i));
#pragma unroll
      for (int i = 0; i < 8; ++i) acc_i[8 + i] += __mul24(pk, nib(cu[k].y, i));
    }
#pragma unroll
    for (int k = 0; k < 16; ++k) cu[k] = nx[k];
  }

  // ---- epilogue: block combine -> atomic into acc_step ----
  const float ds = 9.5367431640625e-7f;  // 2^-20
#pragma unroll
  for (int j = 0; j < 4; ++j)
    ((float4*)s_lin)[wv * (DIMS / 4) + j * 64 + lane] =
        make_float4((float)acc_i[4 * j + 0] * ds, (float)acc_i[4 * j + 1] * ds,
                    (float)acc_i[4 * j + 2] * ds, (float)acc_i[4 * j + 3] * ds);
  __syncthreads();
  float4 sum = ((float4*)s_lin)[tid];
#pragma unroll
  for (int w = 1; w < NWAVE; ++w) {
    float4 b = ((float4*)s_lin)[w * (DIMS / 4) + tid];
    sum.x += b.x; sum.y += b.y; sum.z += b.z; sum.w += b.w;
  }
  float* accS = accbuf + step * ACC_STRIDE;
  atomicAdd(&accS[4 * tid + 0], sum.x);
  atomicAdd(&accS[4 * tid + 1], sum.y);
  atomicAdd(&accS[4 * tid + 2], sum.z);
  atomicAdd(&accS[4 * tid + 3], sum.w);
}

// ---------------- init: zero acc buffers + DG thresholding into cur0 ----------------
__global__ void init_k(const float* __restrict__ iso, float* __restrict__ accbuf) {
  const int idx = blockIdx.x * blockDim.x + threadIdx.x;
  const int nacc = 5 * ACC_STRIDE;
  if (idx < nacc) accbuf[idx] = 0.f;
  else if (idx < nacc + DIMS) {
    const float v = iso[idx - nacc];
    accbuf[idx] = (v > 0.1f) ? v : 0.f;  // cur0 lives right after accbuf
  }
}

// ---------------- final: reconstruct cur_5, write out + mismatch ----------------
__global__ __launch_bounds__(64) void final_k5(const float* __restrict__ iso,
                                               const float* __restrict__ cur0,
                                               const float* __restrict__ accbuf,
                                               float* __restrict__ out) {
  const int lane = threadIdx.x;
  float c[16];
  float w0 = 1.0f;
  for (int t = 0; t < 5; ++t) w0 *= 0.2f;
  const float4* c04 = (const float4*)cur0;
#pragma unroll
  for (int jj = 0; jj < 4; ++jj) {
    float4 t = c04[jj * 64 + lane];
    c[4 * jj + 0] = w0 * t.x; c[4 * jj + 1] = w0 * t.y;
    c[4 * jj + 2] = w0 * t.z; c[4 * jj + 3] = w0 * t.w;
  }
  for (int j = 0; j < 5; ++j) {
    const float lj = accbuf[j * ACC_STRIDE + 1024];
    float coef = 0.8f / lj;
    for (int t = j; t < 4; ++t) coef *= 0.2f;
    const float4* aj = (const float4*)(accbuf + j * ACC_STRIDE);
#pragma unroll
    for (int jj = 0; jj < 4; ++jj) {
      float4 t = aj[jj * 64 + lane];
      c[4 * jj + 0] += coef * t.x; c[4 * jj + 1] += coef * t.y;
      c[4 * jj + 2] += coef * t.z; c[4 * jj + 3] += coef * t.w;
    }
  }
  float ss = 0.f;
#pragma unroll
  for (int jj = 0; jj < 4; ++jj)
#pragma unroll
    for (int i = 0; i < 4; ++i) {
      const int d = 4 * (jj * 64 + lane) + i;
      const float cv = c[4 * jj + i];
      out[d] = cv;
      const float df = iso[d] - cv;
      ss += df * df;
    }
  ss = wave_sum(ss);
  if (lane == 0) out[DIMS] = ss * (1.0f / (float)DIMS);
}

// ---------------- fallback combine + final ----------------
__global__ __launch_bounds__(256) void combine_k(
    const float* __restrict__ part_acc,
    const float* __restrict__ part_l,
    float* __restrict__ cur) {
  const int tid  = threadIdx.x;
  const int lane = tid & 63;
  const int wv   = tid >> 6;
  __shared__ float s_w[NWAVE];
  float lz = 0.f;
  for (int p = tid; p < NB; p += 256) lz += part_l[p];
  lz = wave_sum(lz);
  if (lane == 0) s_w[wv] = lz;
  __syncthreads();
  const float invZ = 1.0f / (s_w[0] + s_w[1] + s_w[2] + s_w[3]);
  const int base = blockIdx.x * 16;
  const int d = tid & 15;
  const int g = tid >> 4;
  float a = 0.f;
  for (int p = g; p < NB; p += 16) a += part_acc[p * DIMS + base + d];
  __shared__ float s_a[16][17];
  s_a[g][d] = a;
  __syncthreads();
#pragma unroll
  for (int s = 8; s; s >>= 1) {
    if (g < s) s_a[g][d] += s_a[g + s][d];
    __syncthreads();
  }
  if (tid < 16) {
    const float retrieved = s_a[0][tid] * invZ;
    const float cc = cur[base + tid];
    cur[base + tid] = 0.8f * retrieved + 0.2f * cc;
  }
}

__global__ __launch_bounds__(256) void final_k(const float* __restrict__ iso,
                                               const float* __restrict__ cur,
                                               float* __restrict__ out) {
  const int tid  = threadIdx.x;
  const int lane = tid & 63;
  const int wv   = tid >> 6;
  float ss = 0.f;
  for (int d = tid; d < DIMS; d += 256) {
    const float c = cur[d];
    out[d] = c;
    const float df = iso[d] - c;
    ss += df * df;
  }
  ss = wave_sum(ss);
  __shared__ float s_w[NWAVE];
  if (lane == 0) s_w[wv] = ss;
  __syncthreads();
  if (tid == 0) out[DIMS] = (s_w[0] + s_w[1] + s_w[2] + s_w[3]) * (1.0f / (float)DIMS);
}

extern "C" void kernel_launch(void* const* d_in, const int* in_sizes, int n_in,
                              void* d_out, int out_size, void* d_ws, size_t ws_size,
                              hipStream_t stream) {
  const float* iso = (const float*)d_in[0];
  const float* ca3 = (const float*)d_in[1];
  float* out = (float*)d_out;
  const int N = in_sizes[1] / DIMS;  // 262144

  // ws layout (floats):
  // accbuf[5*ACC_STRIDE] | cur0[1024] | part_l[NB] | part_acc[NB*1024]
  // | invnorm[N] | rowmeta float2[N] | pai int[N] | qmat uint2[N*64]
  float* ws       = (float*)d_ws;
  float* accbuf   = ws;
  float* cur0     = ws + 5 * ACC_STRIDE;
  float* part_l   = cur0 + DIMS;
  float* part_acc = part_l + NB;
  float* invnorm  = part_acc + (size_t)NB * DIMS;
  float2* rowmeta = (float2*)(invnorm + N);
  int* pai        = (int*)(invnorm + N + 2 * (size_t)N);
  uint2* qmat     = (uint2*)(invnorm + N + 3 * (size_t)N);

  const size_t need_bytes =
      (size_t)(5 * ACC_STRIDE + DIMS + NB + NB * DIMS + N) * 4 +
      (size_t)N * 8 + (size_t)N * 4 + (size_t)N * 512;
  const bool use_i4 = (ws_size >= need_bytes);

  const int rows_per_block = N / NB;  // 256
  const int init_elems = 5 * ACC_STRIDE + DIMS;
  init_k<<<(init_elems + 255) / 256, 256, 0, stream>>>(iso, accbuf);

  if (use_i4) {
    pass_f32<1, 1><<<NB, TPB, 0, stream>>>(ca3, cur0, invnorm, qmat, rowmeta,
                                           accbuf, part_acc, part_l, rows_per_block);
    for (int s = 1; s < 5; ++s) {
      pass_dot<<<NB, TPB, 0, stream>>>((const uint4*)qmat, cur0, rowmeta, accbuf,
                                       pai, s, rows_per_block);
      pass_acc<<<NB, TPB, 0, stream>>>(qmat, pai, accbuf, s, rows_per_block);
    }
    final_k5<<<1, 64, 0, stream>>>(iso, cur0, accbuf, out);
  } else {
    for (int s = 0; s < 5; ++s) {
      if (s == 0)
        pass_f32<1, 0><<<NB, TPB, 0, stream>>>(ca3, cur0, invnorm, qmat, rowmeta,
                                               accbuf, part_acc, part_l, rows_per_block);
      else
        pass_f32<0, 0><<<NB, TPB, 0, stream>>>(ca3, cur0, invnorm, qmat, rowmeta,
                                               accbuf, part_acc, part_l, rows_per_block);
      combine_k<<<CB, 256, 0, stream>>>(part_acc, part_l, cur0);
    }
    final_k<<<1, 256, 0, stream>>>(iso, cur0, out);
  }
}

// Round 10
// 796.852 us; speedup vs baseline: 1.1462x; 1.1462x over previous
//
#include <hip/hip_runtime.h>

#define DIMS 1024
#define NB 1024         // pass blocks
#define TPB 256
#define NWAVE 4
#define CB 64           // fallback combine blocks
#define ACC_STRIDE 1088 // per-step accumulator stride (1024 dims + l + pad)

#if defined(__has_builtin)
#if __has_builtin(__builtin_amdgcn_sdot8)
#define HAVE_SDOT8 1
#endif
#endif
#ifndef HAVE_SDOT8
#define HAVE_SDOT8 0
#endif

typedef unsigned int uintx2 __attribute__((ext_vector_type(2)));
typedef float floatx4 __attribute__((ext_vector_type(4)));

__device__ __forceinline__ uint2 ntload_u2(const uint2* p) {
  uintx2 v = __builtin_nontemporal_load((const uintx2*)p);
  return make_uint2(v.x, v.y);
}
__device__ __forceinline__ void ntstore_u2(uint2* p, uint2 v) {
  uintx2 t; t.x = v.x; t.y = v.y;
  __builtin_nontemporal_store(t, (uintx2*)p);
}
__device__ __forceinline__ float4 ntload_f4(const float4* p) {
  floatx4 v = __builtin_nontemporal_load((const floatx4*)p);
  return make_float4(v.x, v.y, v.z, v.w);
}

__device__ __forceinline__ float wave_sum(float v) {
#pragma unroll
  for (int s = 32; s; s >>= 1) v += __shfl_xor(v, s, 64);
  return v;
}

__device__ __forceinline__ int wave_sum_i(int v) {
#pragma unroll
  for (int s = 32; s; s >>= 1) v += __shfl_xor(v, s, 64);
  return v;
}

__device__ __forceinline__ float wave_max(float v) {
#pragma unroll
  for (int s = 32; s; s >>= 1) v = fmaxf(v, __shfl_xor(v, s, 64));
  return v;
}

__device__ __forceinline__ int nib(unsigned int w, int i) {
  return (int)(w << (28 - 4 * i)) >> 28;
}

// encode 16 f32 (4x float4, qx-order) -> 16 signed int4 nibbles in uint2
__device__ __forceinline__ uint2 enc_i4(const float4* xv, float scale) {
  unsigned int w[2];
#pragma unroll
  for (int h = 0; h < 2; ++h) {
    unsigned int a = 0;
#pragma unroll
    for (int jj = 0; jj < 2; ++jj) {
      float4 t = xv[h * 2 + jj];
      a |= ((unsigned int)((int)rintf(t.x * scale) & 0xF)) << (jj * 16 + 0);
      a |= ((unsigned int)((int)rintf(t.y * scale) & 0xF)) << (jj * 16 + 4);
      a |= ((unsigned int)((int)rintf(t.z * scale) & 0xF)) << (jj * 16 + 8);
      a |= ((unsigned int)((int)rintf(t.w * scale) & 0xF)) << (jj * 16 + 12);
    }
    w[h] = a;
  }
  return make_uint2(w[0], w[1]);
}

// ---------------- f32 pass: fixed-offset softmax (p = exp(sim-1)) ----------
// STEP0: compute invnorm.  MODE: 0 = fallback (part_acc/part_l), 1 = quant-write + atomic acc0.
template <int STEP0, int MODE>
__global__ __launch_bounds__(TPB) void pass_f32(
    const float* __restrict__ ca3,
    const float* __restrict__ q,
    float* __restrict__ invnorm,
    uint2* __restrict__ qmat,
    float2* __restrict__ rowmeta,
    float* __restrict__ accbuf,
    float* __restrict__ part_acc,
    float* __restrict__ part_l,
    int rows_per_block) {
  const int tid  = threadIdx.x;
  const int lane = tid & 63;
  const int wv   = tid >> 6;
  const int bid  = blockIdx.x;

  const float4* q4 = (const float4*)q;
  float4 qv[4];
  float qss = 0.f;
#pragma unroll
  for (int j = 0; j < 4; ++j) {
    float4 t = q4[j * 64 + lane];
    qv[j] = t;
    qss += t.x * t.x + t.y * t.y + t.z * t.z + t.w * t.w;
  }
  qss = wave_sum(qss);
  const float inv_qn = 1.0f / fmaxf(sqrtf(qss), 1e-8f);

  const int rpw = rows_per_block >> 2;
  const long long row0 = (long long)bid * rows_per_block + (long long)wv * rpw;

  float l = 0.f;
  float4 acc[4];
#pragma unroll
  for (int j = 0; j < 4; ++j) acc[j] = make_float4(0.f, 0.f, 0.f, 0.f);

  for (int r = 0; r < rpw; r += 2) {
    const long long rowA = row0 + r;
    const long long rowB = rowA + 1;
    const float4* xA4 = (const float4*)(ca3 + rowA * (long long)DIMS);
    const float4* xB4 = (const float4*)(ca3 + rowB * (long long)DIMS);
    float innA = 0.f, innB = 0.f;
    if (!STEP0) { innA = invnorm[rowA]; innB = invnorm[rowB]; }
    float4 xa[4], xb[4];
#pragma unroll
    for (int j = 0; j < 4; ++j) xa[j] = ntload_f4(&xA4[j * 64 + lane]);
#pragma unroll
    for (int j = 0; j < 4; ++j) xb[j] = ntload_f4(&xB4[j * 64 + lane]);

    float dA = 0.f, dB = 0.f, rnA = 0.f, rnB = 0.f, mxA = 0.f, mxB = 0.f;
#pragma unroll
    for (int j = 0; j < 4; ++j) {
      dA += xa[j].x * qv[j].x + xa[j].y * qv[j].y + xa[j].z * qv[j].z + xa[j].w * qv[j].w;
      dB += xb[j].x * qv[j].x + xb[j].y * qv[j].y + xb[j].z * qv[j].z + xb[j].w * qv[j].w;
      if (STEP0) {
        rnA += xa[j].x * xa[j].x + xa[j].y * xa[j].y + xa[j].z * xa[j].z + xa[j].w * xa[j].w;
        rnB += xb[j].x * xb[j].x + xb[j].y * xb[j].y + xb[j].z * xb[j].z + xb[j].w * xb[j].w;
      }
      if (MODE) {
        mxA = fmaxf(mxA, fmaxf(fmaxf(fabsf(xa[j].x), fabsf(xa[j].y)),
                               fmaxf(fabsf(xa[j].z), fabsf(xa[j].w))));
        mxB = fmaxf(mxB, fmaxf(fmaxf(fabsf(xb[j].x), fabsf(xb[j].y)),
                               fmaxf(fabsf(xb[j].z), fabsf(xb[j].w))));
      }
    }
    dA = wave_sum(dA);
    dB = wave_sum(dB);
    if (STEP0) {
      rnA = wave_sum(rnA);
      rnB = wave_sum(rnB);
      innA = 1.0f / fmaxf(sqrtf(rnA), 1e-8f);
      innB = 1.0f / fmaxf(sqrtf(rnB), 1e-8f);
      if (lane == 0) { invnorm[rowA] = innA; invnorm[rowB] = innB; }
    }
    if (MODE) {
      mxA = wave_max(mxA);
      mxB = wave_max(mxB);
      const float scA = 7.0f / fmaxf(mxA, 1e-20f);
      const float scB = 7.0f / fmaxf(mxB, 1e-20f);
      ntstore_u2(&qmat[rowA * 64 + lane], enc_i4(xa, scA));
      ntstore_u2(&qmat[rowB * 64 + lane], enc_i4(xb, scB));
      if (lane == 0) {
        const float isA = mxA * (1.0f / 7.0f);
        const float isB = mxB * (1.0f / 7.0f);
        rowmeta[rowA] = make_float2(isA * innA, isA);
        rowmeta[rowB] = make_float2(isB * innB, isB);
      }
    }
    const float pA = __expf(dA * innA * inv_qn - 1.0f);
    const float pB = __expf(dB * innB * inv_qn - 1.0f);
    l += pA + pB;
#pragma unroll
    for (int j = 0; j < 4; ++j) {
      acc[j].x += pA * xa[j].x + pB * xb[j].x;
      acc[j].y += pA * xa[j].y + pB * xb[j].y;
      acc[j].z += pA * xa[j].z + pB * xb[j].z;
      acc[j].w += pA * xa[j].w + pB * xb[j].w;
    }
  }

  // ---- block combine ----
  __shared__ float s_l[NWAVE];
  __shared__ float s_lin[NWAVE * DIMS];  // 16 KB
  if (lane == 0) s_l[wv] = l;
#pragma unroll
  for (int j = 0; j < 4; ++j)
    ((float4*)s_lin)[wv * (DIMS / 4) + j * 64 + lane] = acc[j];
  __syncthreads();
  float4 sum = ((float4*)s_lin)[tid];
#pragma unroll
  for (int w = 1; w < NWAVE; ++w) {
    float4 b = ((float4*)s_lin)[w * (DIMS / 4) + tid];
    sum.x += b.x; sum.y += b.y; sum.z += b.z; sum.w += b.w;
  }
  if (MODE) {
    atomicAdd(&accbuf[4 * tid + 0], sum.x);
    atomicAdd(&accbuf[4 * tid + 1], sum.y);
    atomicAdd(&accbuf[4 * tid + 2], sum.z);
    atomicAdd(&accbuf[4 * tid + 3], sum.w);
    if (tid == 0) atomicAdd(&accbuf[1024], s_l[0] + s_l[1] + s_l[2] + s_l[3]);
  } else {
    ((float4*)part_acc)[bid * (DIMS / 4) + tid] = sum;
    if (tid == 0) part_l[bid] = s_l[0] + s_l[1] + s_l[2] + s_l[3];
  }
}

// ---------------- int4 pass (R6 structure + nt loads + inline reconstruction) --------
__device__ __forceinline__ void process4(const uint2* u, const float2* m, unsigned int qq0,
                                         unsigned int qq1, float qscale, float inv_qn,
                                         float& l, int* acc_i) {
  int d[4];
#pragma unroll
  for (int k = 0; k < 4; ++k) {
#if HAVE_SDOT8
    int t = __builtin_amdgcn_sdot8((int)u[k].x, (int)qq0, 0, false);
    t = __builtin_amdgcn_sdot8((int)u[k].y, (int)qq1, t, false);
#else
    int t = 0;
#pragma unroll
    for (int i = 0; i < 8; ++i) t += __mul24(nib(u[k].x, i), nib(qq0, i));
#pragma unroll
    for (int i = 0; i < 8; ++i) t += __mul24(nib(u[k].y, i), nib(qq1, i));
#endif
    d[k] = t;
  }
#pragma unroll
  for (int k = 0; k < 4; ++k) d[k] = wave_sum_i(d[k]);
#pragma unroll
  for (int k = 0; k < 4; ++k) {
    const float p = __expf((float)d[k] * m[k].x * qscale * inv_qn - 1.0f);
    l += p;
    const int pai = (int)(p * m[k].y * 1048576.0f + 0.5f);  // < 2^24
#pragma unroll
    for (int i = 0; i < 8; ++i) acc_i[i]     += __mul24(pai, nib(u[k].x, i));
#pragma unroll
    for (int i = 0; i < 8; ++i) acc_i[8 + i] += __mul24(pai, nib(u[k].y, i));
  }
}

__global__ __launch_bounds__(TPB, 4) void pass_i4(
    const uint2* __restrict__ qmat,     // row = 64 uint2 (512 B)
    const float* __restrict__ cur0,
    const float2* __restrict__ rowmeta, // {inv_scale*invnorm, inv_scale}
    float* __restrict__ accbuf,
    int step,                           // s in 1..4
    int rows_per_block) {
  const int tid  = threadIdx.x;
  const int lane = tid & 63;
  const int wv   = tid >> 6;
  const int bid  = blockIdx.x;

  // ---- per-thread reconstruction of cur_step (qx-order: dims 4*(j*64+lane)+i) ----
  float c[16];
  float w0 = 1.0f;
  for (int t = 0; t < step; ++t) w0 *= 0.2f;
  const float4* c04 = (const float4*)cur0;
#pragma unroll
  for (int j = 0; j < 4; ++j) {
    float4 t = c04[j * 64 + lane];
    c[4 * j + 0] = w0 * t.x; c[4 * j + 1] = w0 * t.y;
    c[4 * j + 2] = w0 * t.z; c[4 * j + 3] = w0 * t.w;
  }
  for (int j = 0; j < step; ++j) {
    const float lj = accbuf[j * ACC_STRIDE + 1024];
    float coef = 0.8f / lj;
    for (int t = j; t < step - 1; ++t) coef *= 0.2f;
    const float4* aj = (const float4*)(accbuf + j * ACC_STRIDE);
#pragma unroll
    for (int jj = 0; jj < 4; ++jj) {
      float4 t = aj[jj * 64 + lane];
      c[4 * jj + 0] += coef * t.x; c[4 * jj + 1] += coef * t.y;
      c[4 * jj + 2] += coef * t.z; c[4 * jj + 3] += coef * t.w;
    }
  }
  float qss = 0.f, qmx = 0.f;
#pragma unroll
  for (int i = 0; i < 16; ++i) { qss += c[i] * c[i]; qmx = fmaxf(qmx, fabsf(c[i])); }
  qss = wave_sum(qss);
  qmx = wave_max(qmx);
  const float inv_qn = 1.0f / fmaxf(sqrtf(qss), 1e-8f);
  const float sq = 7.0f / fmaxf(qmx, 1e-20f);
  unsigned int qq0 = 0, qq1 = 0;
#pragma unroll
  for (int i = 0; i < 8; ++i)
    qq0 |= ((unsigned int)((int)rintf(c[i] * sq) & 0xF)) << (4 * i);
#pragma unroll
  for (int i = 0; i < 8; ++i)
    qq1 |= ((unsigned int)((int)rintf(c[8 + i] * sq) & 0xF)) << (4 * i);
  const float qscale = qmx * (1.0f / 7.0f);

  // ---- main loop: 64 rows/wave, 4-row groups, A/B prefetch, nt loads ----
  const int rpw = rows_per_block >> 2;
  const long long row0 = (long long)bid * rows_per_block + (long long)wv * rpw;
  const uint2* base = qmat + row0 * 64;
  const float2* metab = rowmeta + row0;

  float l = 0.f;
  int acc_i[16];
#pragma unroll
  for (int i = 0; i < 16; ++i) acc_i[i] = 0;

  uint2 ua[4], ub[4];
  float2 ma[4], mb[4];
#pragma unroll
  for (int k = 0; k < 4; ++k) { ua[k] = ntload_u2(&base[k * 64 + lane]); ma[k] = metab[k]; }

  const int ng = rpw >> 2;  // 16 groups of 4 rows
  for (int g = 0; g < ng; g += 2) {
    const int gB = g + 1;
    const int gA2 = (g + 2 < ng) ? (g + 2) : 0;
#pragma unroll
    for (int k = 0; k < 4; ++k) {
      ub[k] = ntload_u2(&base[(gB * 4 + k) * 64 + lane]);
      mb[k] = metab[gB * 4 + k];
    }
    process4(ua, ma, qq0, qq1, qscale, inv_qn, l, acc_i);
#pragma unroll
    for (int k = 0; k < 4; ++k) {
      ua[k] = ntload_u2(&base[(gA2 * 4 + k) * 64 + lane]);
      ma[k] = metab[gA2 * 4 + k];
    }
    process4(ub, mb, qq0, qq1, qscale, inv_qn, l, acc_i);
  }

  // ---- epilogue: block combine -> atomic into acc_step ----
  __shared__ float s_l[NWAVE];
  __shared__ float s_lin[NWAVE * DIMS];  // 16 KB
  if (lane == 0) s_l[wv] = l;
  const float ds = 9.5367431640625e-7f;  // 2^-20
#pragma unroll
  for (int j = 0; j < 4; ++j)
    ((float4*)s_lin)[wv * (DIMS / 4) + j * 64 + lane] =
        make_float4((float)acc_i[4 * j + 0] * ds, (float)acc_i[4 * j + 1] * ds,
                    (float)acc_i[4 * j + 2] * ds, (float)acc_i[4 * j + 3] * ds);
  __syncthreads();
  float4 sum = ((float4*)s_lin)[tid];
#pragma unroll
  for (int w = 1; w < NWAVE; ++w) {
    float4 b = ((float4*)s_lin)[w * (DIMS / 4) + tid];
    sum.x += b.x; sum.y += b.y; sum.z += b.z; sum.w += b.w;
  }
  float* accS = accbuf + step * ACC_STRIDE;
  atomicAdd(&accS[4 * tid + 0], sum.x);
  atomicAdd(&accS[4 * tid + 1], sum.y);
  atomicAdd(&accS[4 * tid + 2], sum.z);
  atomicAdd(&accS[4 * tid + 3], sum.w);
  if (tid == 0) atomicAdd(&accS[1024], s_l[0] + s_l[1] + s_l[2] + s_l[3]);
}

// ---------------- init: zero acc buffers + DG thresholding into cur0 ----------------
__global__ void init_k(const float* __restrict__ iso, float* __restrict__ accbuf) {
  const int idx = blockIdx.x * blockDim.x + threadIdx.x;
  const int nacc = 5 * ACC_STRIDE;
  if (idx < nacc) accbuf[idx] = 0.f;
  else if (idx < nacc + DIMS) {
    const float v = iso[idx - nacc];
    accbuf[idx] = (v > 0.1f) ? v : 0.f;  // cur0 lives right after accbuf
  }
}

// ---------------- final: reconstruct cur_5, write out + mismatch ----------------
__global__ __launch_bounds__(64) void final_k5(const float* __restrict__ iso,
                                               const float* __restrict__ cur0,
                                               const float* __restrict__ accbuf,
                                               float* __restrict__ out) {
  const int lane = threadIdx.x;
  float c[16];
  float w0 = 1.0f;
  for (int t = 0; t < 5; ++t) w0 *= 0.2f;
  const float4* c04 = (const float4*)cur0;
#pragma unroll
  for (int jj = 0; jj < 4; ++jj) {
    float4 t = c04[jj * 64 + lane];
    c[4 * jj + 0] = w0 * t.x; c[4 * jj + 1] = w0 * t.y;
    c[4 * jj + 2] = w0 * t.z; c[4 * jj + 3] = w0 * t.w;
  }
  for (int j = 0; j < 5; ++j) {
    const float lj = accbuf[j * ACC_STRIDE + 1024];
    float coef = 0.8f / lj;
    for (int t = j; t < 4; ++t) coef *= 0.2f;
    const float4* aj = (const float4*)(accbuf + j * ACC_STRIDE);
#pragma unroll
    for (int jj = 0; jj < 4; ++jj) {
      float4 t = aj[jj * 64 + lane];
      c[4 * jj + 0] += coef * t.x; c[4 * jj + 1] += coef * t.y;
      c[4 * jj + 2] += coef * t.z; c[4 * jj + 3] += coef * t.w;
    }
  }
  float ss = 0.f;
#pragma unroll
  for (int jj = 0; jj < 4; ++jj)
#pragma unroll
    for (int i = 0; i < 4; ++i) {
      const int d = 4 * (jj * 64 + lane) + i;
      const float cv = c[4 * jj + i];
      out[d] = cv;
      const float df = iso[d] - cv;
      ss += df * df;
    }
  ss = wave_sum(ss);
  if (lane == 0) out[DIMS] = ss * (1.0f / (float)DIMS);
}

// ---------------- fallback combine + final ----------------
__global__ __launch_bounds__(256) void combine_k(
    const float* __restrict__ part_acc,
    const float* __restrict__ part_l,
    float* __restrict__ cur) {
  const int tid  = threadIdx.x;
  const int lane = tid & 63;
  const int wv   = tid >> 6;
  __shared__ float s_w[NWAVE];
  float lz = 0.f;
  for (int p = tid; p < NB; p += 256) lz += part_l[p];
  lz = wave_sum(lz);
  if (lane == 0) s_w[wv] = lz;
  __syncthreads();
  const float invZ = 1.0f / (s_w[0] + s_w[1] + s_w[2] + s_w[3]);
  const int base = blockIdx.x * 16;
  const int d = tid & 15;
  const int g = tid >> 4;
  float a = 0.f;
  for (int p = g; p < NB; p += 16) a += part_acc[p * DIMS + base + d];
  __shared__ float s_a[16][17];
  s_a[g][d] = a;
  __syncthreads();
#pragma unroll
  for (int s = 8; s; s >>= 1) {
    if (g < s) s_a[g][d] += s_a[g + s][d];
    __syncthreads();
  }
  if (tid < 16) {
    const float retrieved = s_a[0][tid] * invZ;
    const float cc = cur[base + tid];
    cur[base + tid] = 0.8f * retrieved + 0.2f * cc;
  }
}

__global__ __launch_bounds__(256) void final_k(const float* __restrict__ iso,
                                               const float* __restrict__ cur,
                                               float* __restrict__ out) {
  const int tid  = threadIdx.x;
  const int lane = tid & 63;
  const int wv   = tid >> 6;
  float ss = 0.f;
  for (int d = tid; d < DIMS; d += 256) {
    const float c = cur[d];
    out[d] = c;
    const float df = iso[d] - c;
    ss += df * df;
  }
  ss = wave_sum(ss);
  __shared__ float s_w[NWAVE];
  if (lane == 0) s_w[wv] = ss;
  __syncthreads();
  if (tid == 0) out[DIMS] = (s_w[0] + s_w[1] + s_w[2] + s_w[3]) * (1.0f / (float)DIMS);
}

extern "C" void kernel_launch(void* const* d_in, const int* in_sizes, int n_in,
                              void* d_out, int out_size, void* d_ws, size_t ws_size,
                              hipStream_t stream) {
  const float* iso = (const float*)d_in[0];
  const float* ca3 = (const float*)d_in[1];
  float* out = (float*)d_out;
  const int N = in_sizes[1] / DIMS;  // 262144

  // ws layout (floats):
  // accbuf[5*ACC_STRIDE] | cur0[1024] | part_l[NB] | part_acc[NB*1024]
  // | invnorm[N] | rowmeta float2[N] | qmat uint2[N*64]
  float* ws       = (float*)d_ws;
  float* accbuf   = ws;
  float* cur0     = ws + 5 * ACC_STRIDE;
  float* part_l   = cur0 + DIMS;
  float* part_acc = part_l + NB;
  float* invnorm  = part_acc + (size_t)NB * DIMS;
  float2* rowmeta = (float2*)(invnorm + N);
  uint2* qmat     = (uint2*)(invnorm + N + 2 * (size_t)N);

  const size_t need_bytes =
      (size_t)(5 * ACC_STRIDE + DIMS + NB + NB * DIMS + N) * 4 +
      (size_t)N * 8 + (size_t)N * 512;
  const bool use_i4 = (ws_size >= need_bytes);

  const int rows_per_block = N / NB;  // 256
  const int init_elems = 5 * ACC_STRIDE + DIMS;
  init_k<<<(init_elems + 255) / 256, 256, 0, stream>>>(iso, accbuf);

  if (use_i4) {
    pass_f32<1, 1><<<NB, TPB, 0, stream>>>(ca3, cur0, invnorm, qmat, rowmeta,
                                           accbuf, part_acc, part_l, rows_per_block);
    for (int s = 1; s < 5; ++s)
      pass_i4<<<NB, TPB, 0, stream>>>(qmat, cur0, rowmeta, accbuf, s, rows_per_block);
    final_k5<<<1, 64, 0, stream>>>(iso, cur0, accbuf, out);
  } else {
    for (int s = 0; s < 5; ++s) {
      if (s == 0)
        pass_f32<1, 0><<<NB, TPB, 0, stream>>>(ca3, cur0, invnorm, qmat, rowmeta,
                                               accbuf, part_acc, part_l, rows_per_block);
      else
        pass_f32<0, 0><<<NB, TPB, 0, stream>>>(ca3, cur0, invnorm, qmat, rowmeta,
                                               accbuf, part_acc, part_l, rows_per_block);
      combine_k<<<CB, 256, 0, stream>>>(part_acc, part_l, cur0);
    }
    final_k<<<1, 256, 0, stream>>>(iso, cur0, out);
  }
}